// Round 1
// baseline (5508.318 us; speedup 1.0000x reference)
//
#include <hip/hip_runtime.h>
#include <hip/hip_bf16.h>

#define N_NODES 100000
#define EDGES   1600000
#define D       128
#define NLAYERS 2
#define NEG_SLOPE 0.01f

typedef __attribute__((ext_vector_type(8))) __bf16 bf16x8;
typedef __attribute__((ext_vector_type(4))) float  f32x4;

// ---------------- SpMM: side[row] += val * ego[col]  (edge-parallel, atomics)
__global__ void spmm_atomic_kernel(const float* __restrict__ ego,
                                   const int*   __restrict__ arow,
                                   const int*   __restrict__ acol,
                                   const float* __restrict__ aval,
                                   float*       __restrict__ side) {
    int t = blockIdx.x * blockDim.x + threadIdx.x;
    int e = t >> 5;
    if (e >= EDGES) return;
    int q = t & 31;                       // 32 threads/edge, 4 floats each
    int c = acol[e];
    int r = arow[e];
    float v = aval[e];
    float4 x = *((const float4*)(ego + (size_t)c * D) + q);
    float* dst = side + (size_t)r * D + q * 4;
    atomicAdd(dst + 0, v * x.x);
    atomicAdd(dst + 1, v * x.y);
    atomicAdd(dst + 2, v * x.z);
    atomicAdd(dst + 3, v * x.w);
}

// ---------------- Prepack W (both layers, both mats) into MFMA B-fragment order, bf16.
// Layout: [layer][mat][kc(4)][cf(8)][lane(64)][j(8)], B[k][col],
// k = kc*32 + (lane>>4)*8 + j, col = cf*16 + (lane&15).
__global__ void prepack_kernel(const float* __restrict__ wsum,
                               const float* __restrict__ wprod,
                               __bf16*      __restrict__ wpk) {
    int t = blockIdx.x * blockDim.x + threadIdx.x;   // 65536 total
    int j     = t & 7;
    int lane  = (t >> 3) & 63;
    int cf    = (t >> 9) & 7;
    int kc    = (t >> 12) & 3;
    int mat   = (t >> 14) & 1;
    int layer = (t >> 15) & 1;
    int k   = kc * 32 + (lane >> 4) * 8 + j;
    int col = cf * 16 + (lane & 15);
    const float* W = mat ? wprod : wsum;
    wpk[t] = (__bf16)W[((size_t)layer * D + k) * D + col];
}

// ---------------- Fused dense: out[n] = lrelu((e+s)Wsum+bs) + lrelu((e*s)Wprod+bp)
// 4 waves/block, 16 nodes/wave, full 128 output dims per wave.
__global__ __launch_bounds__(256) void dense_kernel(
    const float*  __restrict__ ego,
    const float*  __restrict__ side,
    const bf16x8* __restrict__ wpk,    // this layer: 2048 sum frags, then 2048 prod frags
    const float*  __restrict__ bsum,   // this layer's 128
    const float*  __restrict__ bprod,
    float*        __restrict__ out) {
    int lane = threadIdx.x & 63;
    int wid  = threadIdx.x >> 6;
    int node_base = blockIdx.x * 64 + wid * 16;
    int arow_node = node_base + (lane & 15);   // A-frag row
    int kgrp = lane >> 4;

    f32x4 acc_s[8], acc_p[8];
#pragma unroll
    for (int i = 0; i < 8; i++) { acc_s[i] = (f32x4)(0.f); acc_p[i] = (f32x4)(0.f); }

    bool avalid = arow_node < N_NODES;
    const float* erow = ego  + (size_t)arow_node * D;
    const float* srow = side + (size_t)arow_node * D;

#pragma unroll
    for (int kc = 0; kc < 4; kc++) {
        int kbase = kc * 32 + kgrp * 8;
        bf16x8 a_s, a_p;
        if (avalid) {
            float4 e0 = *(const float4*)(erow + kbase);
            float4 e1 = *(const float4*)(erow + kbase + 4);
            float4 s0 = *(const float4*)(srow + kbase);
            float4 s1 = *(const float4*)(srow + kbase + 4);
            float es[8] = {e0.x, e0.y, e0.z, e0.w, e1.x, e1.y, e1.z, e1.w};
            float ss[8] = {s0.x, s0.y, s0.z, s0.w, s1.x, s1.y, s1.z, s1.w};
#pragma unroll
            for (int j = 0; j < 8; j++) {
                a_s[j] = (__bf16)(es[j] + ss[j]);
                a_p[j] = (__bf16)(es[j] * ss[j]);
            }
        } else {
#pragma unroll
            for (int j = 0; j < 8; j++) { a_s[j] = (__bf16)0.f; a_p[j] = (__bf16)0.f; }
        }
#pragma unroll
        for (int cf = 0; cf < 8; cf++) {
            bf16x8 bs = wpk[(kc * 8 + cf) * 64 + lane];
            bf16x8 bp = wpk[2048 + (kc * 8 + cf) * 64 + lane];
            acc_s[cf] = __builtin_amdgcn_mfma_f32_16x16x32_bf16(a_s, bs, acc_s[cf], 0, 0, 0);
            acc_p[cf] = __builtin_amdgcn_mfma_f32_16x16x32_bf16(a_p, bp, acc_p[cf], 0, 0, 0);
        }
    }

    // epilogue: C/D layout col = lane&15, row = (lane>>4)*4 + reg
    int colb = lane & 15;
#pragma unroll
    for (int cf = 0; cf < 8; cf++) {
        int d = cf * 16 + colb;
        float bsv = bsum[d], bpv = bprod[d];
#pragma unroll
        for (int r = 0; r < 4; r++) {
            int node = node_base + kgrp * 4 + r;
            if (node < N_NODES) {
                float ys = acc_s[cf][r] + bsv;
                float yp = acc_p[cf][r] + bpv;
                ys = ys >= 0.f ? ys : NEG_SLOPE * ys;
                yp = yp >= 0.f ? yp : NEG_SLOPE * yp;
                out[(size_t)node * D + d] = ys + yp;
            }
        }
    }
}

// ---------------- In-place L2 row-normalize of output slots 1..2 (2N rows)
__global__ void normalize_kernel(float* __restrict__ base) {
    int t = blockIdx.x * blockDim.x + threadIdx.x;
    int rowi = t >> 6;
    int lane = t & 63;
    if (rowi >= 2 * N_NODES) return;
    float2* p = (float2*)(base + (size_t)rowi * D);
    float2 v = p[lane];
    float ss = v.x * v.x + v.y * v.y;
#pragma unroll
    for (int m = 1; m < 64; m <<= 1) ss += __shfl_xor(ss, m, 64);
    float inv = 1.0f / fmaxf(sqrtf(ss), 1e-12f);
    p[lane] = make_float2(v.x * inv, v.y * inv);
}

extern "C" void kernel_launch(void* const* d_in, const int* in_sizes, int n_in,
                              void* d_out, int out_size, void* d_ws, size_t ws_size,
                              hipStream_t stream) {
    const float* emb   = (const float*)d_in[0];
    const int*   arow  = (const int*)d_in[1];
    const int*   acol  = (const int*)d_in[2];
    const float* aval  = (const float*)d_in[3];
    const float* wsum  = (const float*)d_in[4];
    const float* bsum  = (const float*)d_in[5];
    const float* wprod = (const float*)d_in[6];
    const float* bprod = (const float*)d_in[7];
    float* out = (float*)d_out;

    const size_t slot = (size_t)N_NODES * D;          // elements per [N,D] slab
    float*  side = (float*)d_ws;                      // 51.2 MB
    __bf16* wpk  = (__bf16*)((char*)d_ws + slot * 4); // 128 KB, 16B-aligned

    // out slot 0 = embeddings
    hipMemcpyAsync(out, emb, slot * sizeof(float), hipMemcpyDeviceToDevice, stream);

    prepack_kernel<<<65536 / 256, 256, 0, stream>>>(wsum, wprod, wpk);

    const float* ego = emb;
    for (int i = 0; i < NLAYERS; i++) {
        hipMemsetAsync(side, 0, slot * sizeof(float), stream);
        long long spmm_threads = (long long)EDGES * 32;
        spmm_atomic_kernel<<<(int)((spmm_threads + 255) / 256), 256, 0, stream>>>(
            ego, arow, acol, aval, side);
        float* ego_out = out + (size_t)(i + 1) * slot;
        dense_kernel<<<(N_NODES + 63) / 64, 256, 0, stream>>>(
            ego, side, (const bf16x8*)wpk + (size_t)i * 4096,
            bsum + (size_t)i * D, bprod + (size_t)i * D, ego_out);
        ego = ego_out;
    }
    long long nthreads = (long long)2 * N_NODES * 64;
    normalize_kernel<<<(int)((nthreads + 255) / 256), 256, 0, stream>>>(out + slot);
}

// Round 2
// 794.450 us; speedup vs baseline: 6.9335x; 6.9335x over previous
//
#include <hip/hip_runtime.h>
#include <hip/hip_bf16.h>

#define N_NODES 100000
#define EDGES   1600000
#define D       128
#define NLAYERS 2
#define NEG_SLOPE 0.01f

typedef __attribute__((ext_vector_type(8))) __bf16 bf16x8;
typedef __attribute__((ext_vector_type(4))) float  f32x4;

// ---------------- CSR build step 1: row histogram
__global__ void hist_kernel(const int* __restrict__ arow, int* __restrict__ deg) {
    int e = blockIdx.x * 256 + threadIdx.x;
    if (e < EDGES) atomicAdd(&deg[arow[e]], 1);
}

// ---------------- CSR build step 2: single-block exclusive scan (100K elems)
__global__ __launch_bounds__(1024) void scan_kernel(const int* __restrict__ deg,
                                                    int* __restrict__ rowptr,
                                                    int* __restrict__ cursor) {
    __shared__ int part[1024];
    int t = threadIdx.x;
    const int chunk = (N_NODES + 1023) / 1024;   // 98
    int beg = t * chunk;
    int end = beg + chunk; if (end > N_NODES) end = N_NODES;
    int s = 0;
    for (int i = beg; i < end; i++) s += deg[i];
    part[t] = s;
    __syncthreads();
    // Hillis-Steele inclusive scan
    for (int off = 1; off < 1024; off <<= 1) {
        int v = (t >= off) ? part[t - off] : 0;
        __syncthreads();
        part[t] += v;
        __syncthreads();
    }
    int run = (t == 0) ? 0 : part[t - 1];        // exclusive prefix
    for (int i = beg; i < end; i++) {
        rowptr[i] = run; cursor[i] = run; run += deg[i];
    }
    if (t == 1023) rowptr[N_NODES] = run;        // == EDGES
}

// ---------------- CSR build step 3: scatter (col,val) into row buckets
__global__ void scatter_kernel(const int* __restrict__ arow,
                               const int* __restrict__ acol,
                               const float* __restrict__ aval,
                               int*   __restrict__ cursor,
                               int*   __restrict__ ccol,
                               float* __restrict__ cval) {
    int e = blockIdx.x * 256 + threadIdx.x;
    if (e >= EDGES) return;
    int r = arow[e];
    int pos = atomicAdd(&cursor[r], 1);
    ccol[pos] = acol[e];
    cval[pos] = aval[e];
}

// ---------------- SpMM (CSR gather): one wave per row, no atomics
__global__ __launch_bounds__(256) void spmm_csr_kernel(
    const float* __restrict__ ego,
    const int*   __restrict__ rowptr,
    const int*   __restrict__ ccol,
    const float* __restrict__ cval,
    float*       __restrict__ side) {
    int row  = blockIdx.x * 4 + (threadIdx.x >> 6);
    int lane = threadIdx.x & 63;
    if (row >= N_NODES) return;
    int beg = rowptr[row], end = rowptr[row + 1];
    float2 acc = make_float2(0.f, 0.f);
    int e = beg;
    // 2-deep unroll for a little MLP on the gathered rows
    for (; e + 2 <= end; e += 2) {
        int   c0 = ccol[e],     c1 = ccol[e + 1];
        float v0 = cval[e],     v1 = cval[e + 1];
        float2 x0 = *((const float2*)(ego + (size_t)c0 * D) + lane);
        float2 x1 = *((const float2*)(ego + (size_t)c1 * D) + lane);
        acc.x += v0 * x0.x + v1 * x1.x;
        acc.y += v0 * x0.y + v1 * x1.y;
    }
    if (e < end) {
        int c = ccol[e]; float v = cval[e];
        float2 x = *((const float2*)(ego + (size_t)c * D) + lane);
        acc.x += v * x.x; acc.y += v * x.y;
    }
    *((float2*)(side + (size_t)row * D) + lane) = acc;
}

// ---------------- Prepack W (both layers, both mats) into MFMA B-fragment order, bf16.
__global__ void prepack_kernel(const float* __restrict__ wsum,
                               const float* __restrict__ wprod,
                               __bf16*      __restrict__ wpk) {
    int t = blockIdx.x * blockDim.x + threadIdx.x;   // 65536 total
    int j     = t & 7;
    int lane  = (t >> 3) & 63;
    int cf    = (t >> 9) & 7;
    int kc    = (t >> 12) & 3;
    int mat   = (t >> 14) & 1;
    int layer = (t >> 15) & 1;
    int k   = kc * 32 + (lane >> 4) * 8 + j;
    int col = cf * 16 + (lane & 15);
    const float* W = mat ? wprod : wsum;
    wpk[t] = (__bf16)W[((size_t)layer * D + k) * D + col];
}

// ---------------- Fused dense: out[n] = lrelu((e+s)Wsum+bs) + lrelu((e*s)Wprod+bp)
__global__ __launch_bounds__(256) void dense_kernel(
    const float*  __restrict__ ego,
    const float*  __restrict__ side,
    const bf16x8* __restrict__ wpk,    // this layer: 2048 sum frags, then 2048 prod frags
    const float*  __restrict__ bsum,
    const float*  __restrict__ bprod,
    float*        __restrict__ out) {
    int lane = threadIdx.x & 63;
    int wid  = threadIdx.x >> 6;
    int node_base = blockIdx.x * 64 + wid * 16;
    int arow_node = node_base + (lane & 15);   // A-frag row
    int kgrp = lane >> 4;

    f32x4 acc_s[8], acc_p[8];
#pragma unroll
    for (int i = 0; i < 8; i++) { acc_s[i] = (f32x4)(0.f); acc_p[i] = (f32x4)(0.f); }

    bool avalid = arow_node < N_NODES;
    const float* erow = ego  + (size_t)arow_node * D;
    const float* srow = side + (size_t)arow_node * D;

#pragma unroll
    for (int kc = 0; kc < 4; kc++) {
        int kbase = kc * 32 + kgrp * 8;
        bf16x8 a_s, a_p;
        if (avalid) {
            float4 e0 = *(const float4*)(erow + kbase);
            float4 e1 = *(const float4*)(erow + kbase + 4);
            float4 s0 = *(const float4*)(srow + kbase);
            float4 s1 = *(const float4*)(srow + kbase + 4);
            float es[8] = {e0.x, e0.y, e0.z, e0.w, e1.x, e1.y, e1.z, e1.w};
            float ss[8] = {s0.x, s0.y, s0.z, s0.w, s1.x, s1.y, s1.z, s1.w};
#pragma unroll
            for (int j = 0; j < 8; j++) {
                a_s[j] = (__bf16)(es[j] + ss[j]);
                a_p[j] = (__bf16)(es[j] * ss[j]);
            }
        } else {
#pragma unroll
            for (int j = 0; j < 8; j++) { a_s[j] = (__bf16)0.f; a_p[j] = (__bf16)0.f; }
        }
#pragma unroll
        for (int cf = 0; cf < 8; cf++) {
            bf16x8 bs = wpk[(kc * 8 + cf) * 64 + lane];
            bf16x8 bp = wpk[2048 + (kc * 8 + cf) * 64 + lane];
            acc_s[cf] = __builtin_amdgcn_mfma_f32_16x16x32_bf16(a_s, bs, acc_s[cf], 0, 0, 0);
            acc_p[cf] = __builtin_amdgcn_mfma_f32_16x16x32_bf16(a_p, bp, acc_p[cf], 0, 0, 0);
        }
    }

    int colb = lane & 15;
#pragma unroll
    for (int cf = 0; cf < 8; cf++) {
        int d = cf * 16 + colb;
        float bsv = bsum[d], bpv = bprod[d];
#pragma unroll
        for (int r = 0; r < 4; r++) {
            int node = node_base + kgrp * 4 + r;
            if (node < N_NODES) {
                float ys = acc_s[cf][r] + bsv;
                float yp = acc_p[cf][r] + bpv;
                ys = ys >= 0.f ? ys : NEG_SLOPE * ys;
                yp = yp >= 0.f ? yp : NEG_SLOPE * yp;
                out[(size_t)node * D + d] = ys + yp;
            }
        }
    }
}

// ---------------- In-place L2 row-normalize of output slots 1..2 (2N rows)
__global__ void normalize_kernel(float* __restrict__ base) {
    int t = blockIdx.x * blockDim.x + threadIdx.x;
    int rowi = t >> 6;
    int lane = t & 63;
    if (rowi >= 2 * N_NODES) return;
    float2* p = (float2*)(base + (size_t)rowi * D);
    float2 v = p[lane];
    float ss = v.x * v.x + v.y * v.y;
#pragma unroll
    for (int m = 1; m < 64; m <<= 1) ss += __shfl_xor(ss, m, 64);
    float inv = 1.0f / fmaxf(sqrtf(ss), 1e-12f);
    p[lane] = make_float2(v.x * inv, v.y * inv);
}

extern "C" void kernel_launch(void* const* d_in, const int* in_sizes, int n_in,
                              void* d_out, int out_size, void* d_ws, size_t ws_size,
                              hipStream_t stream) {
    const float* emb   = (const float*)d_in[0];
    const int*   arow  = (const int*)d_in[1];
    const int*   acol  = (const int*)d_in[2];
    const float* aval  = (const float*)d_in[3];
    const float* wsum  = (const float*)d_in[4];
    const float* bsum  = (const float*)d_in[5];
    const float* wprod = (const float*)d_in[6];
    const float* bprod = (const float*)d_in[7];
    float* out = (float*)d_out;

    const size_t slot = (size_t)N_NODES * D;          // elements per [N,D] slab
    // workspace layout (bytes, 16B aligned)
    char* ws = (char*)d_ws;
    size_t off = 0;
    float*  side   = (float*)(ws + off); off += slot * 4;                 // 51.2 MB
    __bf16* wpk    = (__bf16*)(ws + off); off += 65536 * 2;               // 128 KB
    int*    deg    = (int*)(ws + off); off += (size_t)N_NODES * 4;        // 400 KB
    int*    rowptr = (int*)(ws + off); off += ((size_t)N_NODES + 4) * 4;  // 400 KB
    int*    cursor = (int*)(ws + off); off += (size_t)N_NODES * 4;        // 400 KB
    int*    ccol   = (int*)(ws + off); off += (size_t)EDGES * 4;          // 6.4 MB
    float*  cval   = (float*)(ws + off); off += (size_t)EDGES * 4;        // 6.4 MB

    // ---- CSR build (once, reused by both layers)
    hipMemsetAsync(deg, 0, (size_t)N_NODES * 4, stream);
    hist_kernel<<<(EDGES + 255) / 256, 256, 0, stream>>>(arow, deg);
    scan_kernel<<<1, 1024, 0, stream>>>(deg, rowptr, cursor);
    scatter_kernel<<<(EDGES + 255) / 256, 256, 0, stream>>>(arow, acol, aval, cursor, ccol, cval);

    // out slot 0 = embeddings
    hipMemcpyAsync(out, emb, slot * sizeof(float), hipMemcpyDeviceToDevice, stream);

    prepack_kernel<<<65536 / 256, 256, 0, stream>>>(wsum, wprod, wpk);

    const float* ego = emb;
    for (int i = 0; i < NLAYERS; i++) {
        spmm_csr_kernel<<<(N_NODES + 3) / 4, 256, 0, stream>>>(ego, rowptr, ccol, cval, side);
        float* ego_out = out + (size_t)(i + 1) * slot;
        dense_kernel<<<(N_NODES + 63) / 64, 256, 0, stream>>>(
            ego, side, (const bf16x8*)wpk + (size_t)i * 4096,
            bsum + (size_t)i * D, bprod + (size_t)i * D, ego_out);
        ego = ego_out;
    }
    long long nthreads = (long long)2 * N_NODES * 64;
    normalize_kernel<<<(int)((nthreads + 255) / 256), 256, 0, stream>>>(out + slot);
}

// Round 3
// 546.052 us; speedup vs baseline: 10.0875x; 1.4549x over previous
//
#include <hip/hip_runtime.h>
#include <hip/hip_bf16.h>

#define N_NODES 100000
#define EDGES   1600000
#define D       128
#define NLAYERS 2
#define NEG_SLOPE 0.01f
#define NB ((N_NODES + 255) / 256)   // 391 scan blocks

typedef __attribute__((ext_vector_type(8))) __bf16 bf16x8;
typedef __attribute__((ext_vector_type(4))) float  f32x4;

// ---------------- CSR build step 1: row histogram
__global__ void hist_kernel(const int* __restrict__ arow, int* __restrict__ deg) {
    int e = blockIdx.x * 256 + threadIdx.x;
    if (e < EDGES) atomicAdd(&deg[arow[e]], 1);
}

// ---------------- CSR build step 2a: per-block reduce of deg
__global__ __launch_bounds__(256) void reduce_deg_kernel(const int* __restrict__ deg,
                                                         int* __restrict__ bsum) {
    __shared__ int sh[256];
    int t = threadIdx.x, i = blockIdx.x * 256 + t;
    sh[t] = (i < N_NODES) ? deg[i] : 0;
    __syncthreads();
    for (int off = 128; off > 0; off >>= 1) {
        if (t < off) sh[t] += sh[t + off];
        __syncthreads();
    }
    if (t == 0) bsum[blockIdx.x] = sh[0];
}

// ---------------- CSR build step 2b: single-block scan of 391 partials
__global__ __launch_bounds__(512) void scan_partials_kernel(const int* __restrict__ bsum,
                                                            int* __restrict__ boff,
                                                            int* __restrict__ rowptr) {
    __shared__ int sh[512];
    int t = threadIdx.x;
    int v = (t < NB) ? bsum[t] : 0;
    sh[t] = v;
    __syncthreads();
    for (int off = 1; off < 512; off <<= 1) {
        int u = (t >= off) ? sh[t - off] : 0;
        __syncthreads();
        sh[t] += u;
        __syncthreads();
    }
    if (t < NB) boff[t] = sh[t] - v;          // exclusive
    if (t == 0) rowptr[N_NODES] = sh[NB - 1]; // total == EDGES
}

// ---------------- CSR build step 2c: block-local scan + offset -> rowptr/cursor
__global__ __launch_bounds__(256) void scan_rows_kernel(const int* __restrict__ deg,
                                                        const int* __restrict__ boff,
                                                        int* __restrict__ rowptr,
                                                        int* __restrict__ cursor) {
    __shared__ int sh[256];
    int t = threadIdx.x, i = blockIdx.x * 256 + t;
    int d = (i < N_NODES) ? deg[i] : 0;
    sh[t] = d;
    __syncthreads();
    for (int off = 1; off < 256; off <<= 1) {
        int u = (t >= off) ? sh[t - off] : 0;
        __syncthreads();
        sh[t] += u;
        __syncthreads();
    }
    if (i < N_NODES) {
        int p = boff[blockIdx.x] + sh[t] - d;
        rowptr[i] = p;
        cursor[i] = p;
    }
}

// ---------------- CSR build step 3: scatter (col,val) into row buckets
__global__ void scatter_kernel(const int* __restrict__ arow,
                               const int* __restrict__ acol,
                               const float* __restrict__ aval,
                               int*   __restrict__ cursor,
                               int*   __restrict__ ccol,
                               float* __restrict__ cval) {
    int e = blockIdx.x * 256 + threadIdx.x;
    if (e >= EDGES) return;
    int r = arow[e];
    int pos = atomicAdd(&cursor[r], 1);
    ccol[pos] = acol[e];
    cval[pos] = aval[e];
}

// ---------------- f32 -> bf16 convert (vectorized, 8 elems/thread)
__global__ void f32_to_bf16_kernel(const float* __restrict__ in,
                                   __bf16* __restrict__ out) {
    int t = blockIdx.x * 256 + threadIdx.x;   // N*D/8 threads
    if (t >= N_NODES * D / 8) return;
    const float4* p = (const float4*)in + (size_t)t * 2;
    float4 a = p[0], b = p[1];
    bf16x8 o;
    o[0] = (__bf16)a.x; o[1] = (__bf16)a.y; o[2] = (__bf16)a.z; o[3] = (__bf16)a.w;
    o[4] = (__bf16)b.x; o[5] = (__bf16)b.y; o[6] = (__bf16)b.z; o[7] = (__bf16)b.w;
    *((bf16x8*)out + t) = o;
}

// ---------------- SpMM (CSR gather, bf16 ego): one wave per row, no atomics
__global__ __launch_bounds__(256) void spmm_csr_kernel(
    const unsigned* __restrict__ ego_bf,   // N x D bf16, read as uint (2 elems)
    const int*   __restrict__ rowptr,
    const int*   __restrict__ ccol,
    const float* __restrict__ cval,
    float*       __restrict__ side) {
    int row  = blockIdx.x * 4 + (threadIdx.x >> 6);
    int lane = threadIdx.x & 63;
    if (row >= N_NODES) return;
    int beg = rowptr[row], end = rowptr[row + 1];
    float2 acc = make_float2(0.f, 0.f);
    int e = beg;
    for (; e + 2 <= end; e += 2) {
        int   c0 = ccol[e],     c1 = ccol[e + 1];
        float v0 = cval[e],     v1 = cval[e + 1];
        unsigned u0 = ego_bf[(size_t)c0 * (D / 2) + lane];
        unsigned u1 = ego_bf[(size_t)c1 * (D / 2) + lane];
        acc.x += v0 * __uint_as_float(u0 << 16) + v1 * __uint_as_float(u1 << 16);
        acc.y += v0 * __uint_as_float(u0 & 0xffff0000u) + v1 * __uint_as_float(u1 & 0xffff0000u);
    }
    if (e < end) {
        int c = ccol[e]; float v = cval[e];
        unsigned u = ego_bf[(size_t)c * (D / 2) + lane];
        acc.x += v * __uint_as_float(u << 16);
        acc.y += v * __uint_as_float(u & 0xffff0000u);
    }
    *((float2*)(side + (size_t)row * D) + lane) = acc;
}

// ---------------- Prepack W (both layers, both mats) into MFMA B-fragment order, bf16.
__global__ void prepack_kernel(const float* __restrict__ wsum,
                               const float* __restrict__ wprod,
                               __bf16*      __restrict__ wpk) {
    int t = blockIdx.x * blockDim.x + threadIdx.x;   // 65536 total
    int j     = t & 7;
    int lane  = (t >> 3) & 63;
    int cf    = (t >> 9) & 7;
    int kc    = (t >> 12) & 3;
    int mat   = (t >> 14) & 1;
    int layer = (t >> 15) & 1;
    int k   = kc * 32 + (lane >> 4) * 8 + j;
    int col = cf * 16 + (lane & 15);
    const float* W = mat ? wprod : wsum;
    wpk[t] = (__bf16)W[((size_t)layer * D + k) * D + col];
}

// ---------------- Fused dense: out[n] = lrelu((e+s)Wsum+bs) + lrelu((e*s)Wprod+bp)
__global__ __launch_bounds__(256) void dense_kernel(
    const float*  __restrict__ ego,
    const float*  __restrict__ side,
    const bf16x8* __restrict__ wpk,    // this layer: 2048 sum frags, then 2048 prod frags
    const float*  __restrict__ bsum,
    const float*  __restrict__ bprod,
    float*        __restrict__ out,
    __bf16*       __restrict__ out_bf) {  // optional bf16 copy for next layer's spmm
    int lane = threadIdx.x & 63;
    int wid  = threadIdx.x >> 6;
    int node_base = blockIdx.x * 64 + wid * 16;
    int arow_node = node_base + (lane & 15);   // A-frag row
    int kgrp = lane >> 4;

    f32x4 acc_s[8], acc_p[8];
#pragma unroll
    for (int i = 0; i < 8; i++) { acc_s[i] = (f32x4)(0.f); acc_p[i] = (f32x4)(0.f); }

    bool avalid = arow_node < N_NODES;
    const float* erow = ego  + (size_t)arow_node * D;
    const float* srow = side + (size_t)arow_node * D;

#pragma unroll
    for (int kc = 0; kc < 4; kc++) {
        int kbase = kc * 32 + kgrp * 8;
        bf16x8 a_s, a_p;
        if (avalid) {
            float4 e0 = *(const float4*)(erow + kbase);
            float4 e1 = *(const float4*)(erow + kbase + 4);
            float4 s0 = *(const float4*)(srow + kbase);
            float4 s1 = *(const float4*)(srow + kbase + 4);
            float es[8] = {e0.x, e0.y, e0.z, e0.w, e1.x, e1.y, e1.z, e1.w};
            float ss[8] = {s0.x, s0.y, s0.z, s0.w, s1.x, s1.y, s1.z, s1.w};
#pragma unroll
            for (int j = 0; j < 8; j++) {
                a_s[j] = (__bf16)(es[j] + ss[j]);
                a_p[j] = (__bf16)(es[j] * ss[j]);
            }
        } else {
#pragma unroll
            for (int j = 0; j < 8; j++) { a_s[j] = (__bf16)0.f; a_p[j] = (__bf16)0.f; }
        }
#pragma unroll
        for (int cf = 0; cf < 8; cf++) {
            bf16x8 bs = wpk[(kc * 8 + cf) * 64 + lane];
            bf16x8 bp = wpk[2048 + (kc * 8 + cf) * 64 + lane];
            acc_s[cf] = __builtin_amdgcn_mfma_f32_16x16x32_bf16(a_s, bs, acc_s[cf], 0, 0, 0);
            acc_p[cf] = __builtin_amdgcn_mfma_f32_16x16x32_bf16(a_p, bp, acc_p[cf], 0, 0, 0);
        }
    }

    int colb = lane & 15;
#pragma unroll
    for (int cf = 0; cf < 8; cf++) {
        int d = cf * 16 + colb;
        float bsv = bsum[d], bpv = bprod[d];
#pragma unroll
        for (int r = 0; r < 4; r++) {
            int node = node_base + kgrp * 4 + r;
            if (node < N_NODES) {
                float ys = acc_s[cf][r] + bsv;
                float yp = acc_p[cf][r] + bpv;
                ys = ys >= 0.f ? ys : NEG_SLOPE * ys;
                yp = yp >= 0.f ? yp : NEG_SLOPE * yp;
                float y = ys + yp;
                out[(size_t)node * D + d] = y;
                if (out_bf) out_bf[(size_t)node * D + d] = (__bf16)y;
            }
        }
    }
}

// ---------------- In-place L2 row-normalize of output slots 1..2 (2N rows)
__global__ void normalize_kernel(float* __restrict__ base) {
    int t = blockIdx.x * blockDim.x + threadIdx.x;
    int rowi = t >> 6;
    int lane = t & 63;
    if (rowi >= 2 * N_NODES) return;
    float2* p = (float2*)(base + (size_t)rowi * D);
    float2 v = p[lane];
    float ss = v.x * v.x + v.y * v.y;
#pragma unroll
    for (int m = 1; m < 64; m <<= 1) ss += __shfl_xor(ss, m, 64);
    float inv = 1.0f / fmaxf(sqrtf(ss), 1e-12f);
    p[lane] = make_float2(v.x * inv, v.y * inv);
}

extern "C" void kernel_launch(void* const* d_in, const int* in_sizes, int n_in,
                              void* d_out, int out_size, void* d_ws, size_t ws_size,
                              hipStream_t stream) {
    const float* emb   = (const float*)d_in[0];
    const int*   arow  = (const int*)d_in[1];
    const int*   acol  = (const int*)d_in[2];
    const float* aval  = (const float*)d_in[3];
    const float* wsum  = (const float*)d_in[4];
    const float* bsum  = (const float*)d_in[5];
    const float* wprod = (const float*)d_in[6];
    const float* bprod = (const float*)d_in[7];
    float* out = (float*)d_out;

    const size_t slot = (size_t)N_NODES * D;          // elements per [N,D] slab
    // workspace layout (bytes, 16B aligned)
    char* ws = (char*)d_ws;
    size_t off = 0;
    float*  side   = (float*)(ws + off); off += slot * 4;                 // 51.2 MB
    __bf16* wpk    = (__bf16*)(ws + off); off += 65536 * 2;               // 128 KB
    int*    deg    = (int*)(ws + off); off += (size_t)N_NODES * 4;        // 400 KB
    int*    rowptr = (int*)(ws + off); off += ((size_t)N_NODES + 4) * 4;  // 400 KB
    int*    cursor = (int*)(ws + off); off += (size_t)N_NODES * 4;        // 400 KB
    int*    ccol   = (int*)(ws + off); off += (size_t)EDGES * 4;          // 6.4 MB
    float*  cval   = (float*)(ws + off); off += (size_t)EDGES * 4;        // 6.4 MB
    int*    bsumP  = (int*)(ws + off); off += (size_t)NB * 4;
    int*    boffP  = (int*)(ws + off); off += (size_t)NB * 4;

    // bf16 ego buffer aliased into out slot 2 (dead until dense layer-2 writes it;
    // all uses are stream-ordered strictly before that write)
    __bf16* ego_bf = (__bf16*)(out + 2 * slot);

    // ---- CSR build (once, reused by both layers)
    hipMemsetAsync(deg, 0, (size_t)N_NODES * 4, stream);
    hist_kernel<<<(EDGES + 255) / 256, 256, 0, stream>>>(arow, deg);
    reduce_deg_kernel<<<NB, 256, 0, stream>>>(deg, bsumP);
    scan_partials_kernel<<<1, 512, 0, stream>>>(bsumP, boffP, rowptr);
    scan_rows_kernel<<<NB, 256, 0, stream>>>(deg, boffP, rowptr, cursor);
    scatter_kernel<<<(EDGES + 255) / 256, 256, 0, stream>>>(arow, acol, aval, cursor, ccol, cval);

    // out slot 0 = embeddings
    hipMemcpyAsync(out, emb, slot * sizeof(float), hipMemcpyDeviceToDevice, stream);

    prepack_kernel<<<65536 / 256, 256, 0, stream>>>(wsum, wprod, wpk);

    // bf16 copy of layer-1 ego (= embeddings)
    f32_to_bf16_kernel<<<(N_NODES * D / 8 + 255) / 256, 256, 0, stream>>>(emb, ego_bf);

    const float* ego = emb;
    for (int i = 0; i < NLAYERS; i++) {
        spmm_csr_kernel<<<(N_NODES + 3) / 4, 256, 0, stream>>>(
            (const unsigned*)ego_bf, rowptr, ccol, cval, side);
        float* ego_out = out + (size_t)(i + 1) * slot;
        // layer 0's dense also emits the bf16 ego for layer 1's spmm (overwrites ego_bf,
        // which spmm above has already fully consumed)
        dense_kernel<<<(N_NODES + 63) / 64, 256, 0, stream>>>(
            ego, side, (const bf16x8*)wpk + (size_t)i * 4096,
            bsum + (size_t)i * D, bprod + (size_t)i * D, ego_out,
            (i == 0) ? ego_bf : (__bf16*)nullptr);
        ego = ego_out;
    }
    long long nthreads = (long long)2 * N_NODES * 64;
    normalize_kernel<<<(int)((nthreads + 255) / 256), 256, 0, stream>>>(out + slot);
}

// Round 4
// 444.207 us; speedup vs baseline: 12.4003x; 1.2293x over previous
//
#include <hip/hip_runtime.h>
#include <hip/hip_bf16.h>

#define N_NODES 100000
#define EDGES   1600000
#define D       128
#define NLAYERS 2
#define NEG_SLOPE 0.01f
#define NB ((N_NODES + 255) / 256)   // 391 scan blocks

typedef __attribute__((ext_vector_type(8))) __bf16 bf16x8;
typedef __attribute__((ext_vector_type(4))) float  f32x4;

__device__ __forceinline__ float bf_lo(unsigned u) { return __uint_as_float(u << 16); }
__device__ __forceinline__ float bf_hi(unsigned u) { return __uint_as_float(u & 0xffff0000u); }

// ---------------- CSR build step 1: row histogram
__global__ void hist_kernel(const int* __restrict__ arow, int* __restrict__ deg) {
    int e = blockIdx.x * 256 + threadIdx.x;
    if (e < EDGES) atomicAdd(&deg[arow[e]], 1);
}

// ---------------- CSR build step 2a: per-block reduce of deg
__global__ __launch_bounds__(256) void reduce_deg_kernel(const int* __restrict__ deg,
                                                         int* __restrict__ bsum) {
    __shared__ int sh[256];
    int t = threadIdx.x, i = blockIdx.x * 256 + t;
    sh[t] = (i < N_NODES) ? deg[i] : 0;
    __syncthreads();
    for (int off = 128; off > 0; off >>= 1) {
        if (t < off) sh[t] += sh[t + off];
        __syncthreads();
    }
    if (t == 0) bsum[blockIdx.x] = sh[0];
}

// ---------------- CSR build step 2b: single-block scan of 391 partials
__global__ __launch_bounds__(512) void scan_partials_kernel(const int* __restrict__ bsum,
                                                            int* __restrict__ boff,
                                                            int* __restrict__ rowptr) {
    __shared__ int sh[512];
    int t = threadIdx.x;
    int v = (t < NB) ? bsum[t] : 0;
    sh[t] = v;
    __syncthreads();
    for (int off = 1; off < 512; off <<= 1) {
        int u = (t >= off) ? sh[t - off] : 0;
        __syncthreads();
        sh[t] += u;
        __syncthreads();
    }
    if (t < NB) boff[t] = sh[t] - v;          // exclusive
    if (t == 0) rowptr[N_NODES] = sh[NB - 1]; // total == EDGES
}

// ---------------- CSR build step 2c: block-local scan + offset -> rowptr/cursor
__global__ __launch_bounds__(256) void scan_rows_kernel(const int* __restrict__ deg,
                                                        const int* __restrict__ boff,
                                                        int* __restrict__ rowptr,
                                                        int* __restrict__ cursor) {
    __shared__ int sh[256];
    int t = threadIdx.x, i = blockIdx.x * 256 + t;
    int d = (i < N_NODES) ? deg[i] : 0;
    sh[t] = d;
    __syncthreads();
    for (int off = 1; off < 256; off <<= 1) {
        int u = (t >= off) ? sh[t - off] : 0;
        __syncthreads();
        sh[t] += u;
        __syncthreads();
    }
    if (i < N_NODES) {
        int p = boff[blockIdx.x] + sh[t] - d;
        rowptr[i] = p;
        cursor[i] = p;
    }
}

// ---------------- CSR build step 3: scatter packed (col,val) into row buckets
__global__ void scatter_kernel(const int* __restrict__ arow,
                               const int* __restrict__ acol,
                               const float* __restrict__ aval,
                               int*   __restrict__ cursor,
                               int2*  __restrict__ cpack) {
    int e = blockIdx.x * 256 + threadIdx.x;
    if (e >= EDGES) return;
    int r = arow[e];
    int pos = atomicAdd(&cursor[r], 1);
    int2 pk;
    pk.x = acol[e];
    pk.y = __float_as_int(aval[e]);
    cpack[pos] = pk;
}

// ---------------- out slot0 = emb (f32) and ego_bf = bf16(emb), one read pass
__global__ void copy_emb_kernel(const float* __restrict__ emb,
                                float* __restrict__ out0,
                                __bf16* __restrict__ bf) {
    int t = blockIdx.x * 256 + threadIdx.x;   // N*D/8 threads
    if (t >= N_NODES * D / 8) return;
    const float4* p = (const float4*)emb + (size_t)t * 2;
    float4 a = p[0], b = p[1];
    ((float4*)out0)[(size_t)t * 2]     = a;
    ((float4*)out0)[(size_t)t * 2 + 1] = b;
    bf16x8 o;
    o[0] = (__bf16)a.x; o[1] = (__bf16)a.y; o[2] = (__bf16)a.z; o[3] = (__bf16)a.w;
    o[4] = (__bf16)b.x; o[5] = (__bf16)b.y; o[6] = (__bf16)b.z; o[7] = (__bf16)b.w;
    *((bf16x8*)bf + t) = o;
}

// ---------------- SpMM (CSR gather, bf16 ego, packed edges): one wave per row
__global__ __launch_bounds__(256) void spmm_csr_kernel(
    const unsigned* __restrict__ ego_bf,   // N x D bf16 as uint pairs
    const int*   __restrict__ rowptr,
    const int2*  __restrict__ cpack,
    float*       __restrict__ side) {
    int row  = blockIdx.x * 4 + (threadIdx.x >> 6);
    int lane = threadIdx.x & 63;
    if (row >= N_NODES) return;
    int beg = rowptr[row], end = rowptr[row + 1];
    float accx = 0.f, accy = 0.f;
    int e = beg;
    for (; e + 4 <= end; e += 4) {
        int2 p0 = cpack[e], p1 = cpack[e + 1], p2 = cpack[e + 2], p3 = cpack[e + 3];
        unsigned u0 = ego_bf[(size_t)p0.x * (D / 2) + lane];
        unsigned u1 = ego_bf[(size_t)p1.x * (D / 2) + lane];
        unsigned u2 = ego_bf[(size_t)p2.x * (D / 2) + lane];
        unsigned u3 = ego_bf[(size_t)p3.x * (D / 2) + lane];
        float v0 = __int_as_float(p0.y), v1 = __int_as_float(p1.y);
        float v2 = __int_as_float(p2.y), v3 = __int_as_float(p3.y);
        accx += v0 * bf_lo(u0) + v1 * bf_lo(u1) + v2 * bf_lo(u2) + v3 * bf_lo(u3);
        accy += v0 * bf_hi(u0) + v1 * bf_hi(u1) + v2 * bf_hi(u2) + v3 * bf_hi(u3);
    }
    for (; e < end; e++) {
        int2 p = cpack[e];
        unsigned u = ego_bf[(size_t)p.x * (D / 2) + lane];
        float v = __int_as_float(p.y);
        accx += v * bf_lo(u);
        accy += v * bf_hi(u);
    }
    *((float2*)(side + (size_t)row * D) + lane) = make_float2(accx, accy);
}

// ---------------- Prepack W (both layers, both mats) into MFMA B-fragment order, bf16.
__global__ void prepack_kernel(const float* __restrict__ wsum,
                               const float* __restrict__ wprod,
                               __bf16*      __restrict__ wpk) {
    int t = blockIdx.x * blockDim.x + threadIdx.x;   // 65536 total
    int j     = t & 7;
    int lane  = (t >> 3) & 63;
    int cf    = (t >> 9) & 7;
    int kc    = (t >> 12) & 3;
    int mat   = (t >> 14) & 1;
    int layer = (t >> 15) & 1;
    int k   = kc * 32 + (lane >> 4) * 8 + j;
    int col = cf * 16 + (lane & 15);
    const float* W = mat ? wprod : wsum;
    wpk[t] = (__bf16)W[((size_t)layer * D + k) * D + col];
}

// ---------------- Fused dense + L2-normalize epilogue.
// y = lrelu((e+s)Wsum+bs) + lrelu((e*s)Wprod+bp)
// out_norm[n] = y / max(||y||,eps)      (the harness output slot)
// rn[n]       = max(||y||,eps)          (so next layer can reconstruct y)
// out_bf[n]   = bf16(y)                 (next layer's spmm input)
// If ego_scale != null, the f32 ego input is normalized and must be scaled
// back by rn_prev[node] on load.
__global__ __launch_bounds__(256) void dense_kernel(
    const float*  __restrict__ ego,
    const float*  __restrict__ ego_scale,  // nullable: per-row un-normalize factor
    const float*  __restrict__ side,
    const bf16x8* __restrict__ wpk,        // this layer: 2048 sum frags, then 2048 prod
    const float*  __restrict__ bsum,
    const float*  __restrict__ bprod,
    float*        __restrict__ out_norm,
    float*        __restrict__ rn,         // nullable
    __bf16*       __restrict__ out_bf) {   // nullable
    int lane = threadIdx.x & 63;
    int wid  = threadIdx.x >> 6;
    int node_base = blockIdx.x * 64 + wid * 16;
    int arow_node = node_base + (lane & 15);   // A-frag row
    int kgrp = lane >> 4;

    f32x4 acc_s[8], acc_p[8];
#pragma unroll
    for (int i = 0; i < 8; i++) { acc_s[i] = (f32x4)(0.f); acc_p[i] = (f32x4)(0.f); }

    bool avalid = arow_node < N_NODES;
    const float* erow = ego  + (size_t)arow_node * D;
    const float* srow = side + (size_t)arow_node * D;
    float esc = (ego_scale && avalid) ? ego_scale[arow_node] : 1.0f;

#pragma unroll
    for (int kc = 0; kc < 4; kc++) {
        int kbase = kc * 32 + kgrp * 8;
        bf16x8 a_s, a_p;
        if (avalid) {
            float4 e0 = *(const float4*)(erow + kbase);
            float4 e1 = *(const float4*)(erow + kbase + 4);
            float4 s0 = *(const float4*)(srow + kbase);
            float4 s1 = *(const float4*)(srow + kbase + 4);
            float es[8] = {e0.x, e0.y, e0.z, e0.w, e1.x, e1.y, e1.z, e1.w};
            float ss[8] = {s0.x, s0.y, s0.z, s0.w, s1.x, s1.y, s1.z, s1.w};
#pragma unroll
            for (int j = 0; j < 8; j++) {
                float ev = es[j] * esc;
                a_s[j] = (__bf16)(ev + ss[j]);
                a_p[j] = (__bf16)(ev * ss[j]);
            }
        } else {
#pragma unroll
            for (int j = 0; j < 8; j++) { a_s[j] = (__bf16)0.f; a_p[j] = (__bf16)0.f; }
        }
#pragma unroll
        for (int cf = 0; cf < 8; cf++) {
            bf16x8 bs = wpk[(kc * 8 + cf) * 64 + lane];
            bf16x8 bp = wpk[2048 + (kc * 8 + cf) * 64 + lane];
            acc_s[cf] = __builtin_amdgcn_mfma_f32_16x16x32_bf16(a_s, bs, acc_s[cf], 0, 0, 0);
            acc_p[cf] = __builtin_amdgcn_mfma_f32_16x16x32_bf16(a_p, bp, acc_p[cf], 0, 0, 0);
        }
    }

    // epilogue: C/D layout col = lane&15, row = (lane>>4)*4 + reg
    int colb = lane & 15;
    float ssq[4] = {0.f, 0.f, 0.f, 0.f};
#pragma unroll
    for (int cf = 0; cf < 8; cf++) {
        int d = cf * 16 + colb;
        float bsv = bsum[d], bpv = bprod[d];
#pragma unroll
        for (int r = 0; r < 4; r++) {
            float ys = acc_s[cf][r] + bsv;
            float yp = acc_p[cf][r] + bpv;
            ys = ys >= 0.f ? ys : NEG_SLOPE * ys;
            yp = yp >= 0.f ? yp : NEG_SLOPE * yp;
            float y = ys + yp;
            acc_s[cf][r] = y;          // reuse acc_s as y storage
            ssq[r] += y * y;
        }
    }
    // row sum-of-squares: reduce across the 16 lanes sharing each node
#pragma unroll
    for (int r = 0; r < 4; r++) {
#pragma unroll
        for (int m = 1; m < 16; m <<= 1) ssq[r] += __shfl_xor(ssq[r], m);
    }
    float nrm[4], inv[4];
#pragma unroll
    for (int r = 0; r < 4; r++) {
        nrm[r] = fmaxf(sqrtf(ssq[r]), 1e-12f);
        inv[r] = 1.0f / nrm[r];
    }
#pragma unroll
    for (int cf = 0; cf < 8; cf++) {
        int d = cf * 16 + colb;
#pragma unroll
        for (int r = 0; r < 4; r++) {
            int node = node_base + kgrp * 4 + r;
            if (node < N_NODES) {
                float y = acc_s[cf][r];
                out_norm[(size_t)node * D + d] = y * inv[r];
                if (out_bf) out_bf[(size_t)node * D + d] = (__bf16)y;
            }
        }
    }
    if (rn && colb == 0) {
#pragma unroll
        for (int r = 0; r < 4; r++) {
            int node = node_base + kgrp * 4 + r;
            if (node < N_NODES) rn[node] = nrm[r];
        }
    }
}

extern "C" void kernel_launch(void* const* d_in, const int* in_sizes, int n_in,
                              void* d_out, int out_size, void* d_ws, size_t ws_size,
                              hipStream_t stream) {
    const float* emb   = (const float*)d_in[0];
    const int*   arow  = (const int*)d_in[1];
    const int*   acol  = (const int*)d_in[2];
    const float* aval  = (const float*)d_in[3];
    const float* wsum  = (const float*)d_in[4];
    const float* bsum  = (const float*)d_in[5];
    const float* wprod = (const float*)d_in[6];
    const float* bprod = (const float*)d_in[7];
    float* out = (float*)d_out;

    const size_t slot = (size_t)N_NODES * D;          // elements per [N,D] slab
    // workspace layout (bytes, 16B aligned)
    char* ws = (char*)d_ws;
    size_t off = 0;
    float*  side   = (float*)(ws + off); off += slot * 4;                 // 51.2 MB
    __bf16* wpk    = (__bf16*)(ws + off); off += 65536 * 2;               // 128 KB
    int*    deg    = (int*)(ws + off); off += (size_t)N_NODES * 4;        // 400 KB
    int*    rowptr = (int*)(ws + off); off += ((size_t)N_NODES + 4) * 4;  // 400 KB
    int*    cursor = (int*)(ws + off); off += (size_t)N_NODES * 4;        // 400 KB
    int2*   cpack  = (int2*)(ws + off); off += (size_t)EDGES * 8;         // 12.8 MB
    int*    bsumP  = (int*)(ws + off); off += (size_t)NB * 4;
    int*    boffP  = (int*)(ws + off); off += (size_t)NB * 4;
    float*  rn     = (float*)(ws + off); off += (size_t)N_NODES * 4;      // 400 KB

    // bf16 ego buffer aliased into out slot 2 (dead until dense layer-2 writes it;
    // all uses are stream-ordered strictly before that write)
    __bf16* ego_bf = (__bf16*)(out + 2 * slot);

    // ---- CSR build (once, reused by both layers)
    hipMemsetAsync(deg, 0, (size_t)N_NODES * 4, stream);
    hist_kernel<<<(EDGES + 255) / 256, 256, 0, stream>>>(arow, deg);
    reduce_deg_kernel<<<NB, 256, 0, stream>>>(deg, bsumP);
    scan_partials_kernel<<<1, 512, 0, stream>>>(bsumP, boffP, rowptr);
    scan_rows_kernel<<<NB, 256, 0, stream>>>(deg, boffP, rowptr, cursor);
    scatter_kernel<<<(EDGES + 255) / 256, 256, 0, stream>>>(arow, acol, aval, cursor, cpack);

    // out slot 0 = embeddings (f32) + bf16 ego for layer-1 spmm, one pass
    copy_emb_kernel<<<(N_NODES * D / 8 + 255) / 256, 256, 0, stream>>>(emb, out, ego_bf);

    prepack_kernel<<<65536 / 256, 256, 0, stream>>>(wsum, wprod, wpk);

    // ---- layer 1
    spmm_csr_kernel<<<(N_NODES + 3) / 4, 256, 0, stream>>>(
        (const unsigned*)ego_bf, rowptr, cpack, side);
    dense_kernel<<<(N_NODES + 63) / 64, 256, 0, stream>>>(
        emb, nullptr, side, (const bf16x8*)wpk,
        bsum, bprod,
        out + slot, rn, ego_bf);   // writes normalized slot1 + rn + bf16(unnorm)

    // ---- layer 2
    spmm_csr_kernel<<<(N_NODES + 3) / 4, 256, 0, stream>>>(
        (const unsigned*)ego_bf, rowptr, cpack, side);
    dense_kernel<<<(N_NODES + 63) / 64, 256, 0, stream>>>(
        out + slot, rn, side, (const bf16x8*)wpk + 4096,
        bsum + D, bprod + D,
        out + 2 * slot, nullptr, nullptr);  // writes normalized slot2
}